// Round 1
// baseline (769.552 us; speedup 1.0000x reference)
//
#include <hip/hip_runtime.h>

typedef unsigned short u16;
typedef unsigned int u32;

using f32x4 = __attribute__((ext_vector_type(4))) float;
using bf16x8 = __attribute__((ext_vector_type(8))) __bf16;

#define S_LEN 2048
#define HID_DIM 4096
#define NH 32
#define NKV 8
#define HD 128
#define QKVN 6144

__device__ __forceinline__ u16 f2b(float f) {
  union { float f; u32 u; } v; v.f = f;
  u32 r = (v.u + 0x7FFFu + ((v.u >> 16) & 1u)) >> 16;
  return (u16)r;
}
__device__ __forceinline__ float b2f(u16 b) {
  union { u32 u; float f; } v; v.u = ((u32)b) << 16;
  return v.f;
}

#define AS1 __attribute__((address_space(1)))
#define AS3 __attribute__((address_space(3)))
__device__ __forceinline__ void gl_lds16(const u16* g, u16* l) {
  __builtin_amdgcn_global_load_lds((const AS1 u32*)g, (AS3 u32*)l, 16, 0, 0);
}

// ---------------- fp32 -> bf16 cast (vectorized, grid-stride) ----------------
__global__ void cast_kernel(const float* __restrict__ src, u16* __restrict__ dst, int n4) {
  int i = blockIdx.x * blockDim.x + threadIdx.x;
  int stride = gridDim.x * blockDim.x;
  for (; i < n4; i += stride) {
    float4 v = ((const float4*)src)[i];
    uint2 o;
    o.x = (u32)f2b(v.x) | ((u32)f2b(v.y) << 16);
    o.y = (u32)f2b(v.z) | ((u32)f2b(v.w) << 16);
    ((uint2*)dst)[i] = o;
  }
}

// ---------------- GEMM: C[M,N] = A[M,K] * B[N,K]^T  (bf16 in, f32 acc) -------
// 128x128 tile, BK=32, 4 waves each computing 64x64 (4x4 MFMA 16x16x32).
__global__ __launch_bounds__(256) void gemm_bt(
    const u16* __restrict__ A, const u16* __restrict__ B, void* __restrict__ Cout,
    int M, int N, int K, int c_is_bf16)
{
  __shared__ __align__(16) u16 As[128 * 32];
  __shared__ __align__(16) u16 Bs[128 * 32];
  const int tid  = threadIdx.x;
  const int lane = tid & 63;
  const int wave = tid >> 6;
  const int bn = blockIdx.x * 128;
  const int bm = blockIdx.y * 128;
  const int wm = (wave >> 1) * 64;
  const int wn = (wave & 1) * 64;
  const int lr = lane & 15;
  const int lg = lane >> 4;

  f32x4 acc[4][4] = {};

  const int r = tid >> 2;           // staging row 0..63
  const u16* aG = A + (size_t)(bm + r) * K + (tid & 3) * 8;
  const u16* bG = B + (size_t)(bn + r) * K + (tid & 3) * 8;
  u16* asD = As + tid * 8;          // 16 B per thread, lane-contiguous per wave
  u16* bsD = Bs + tid * 8;

  for (int k0 = 0; k0 < K; k0 += 32) {
    gl_lds16(aG + k0, asD);
    gl_lds16(aG + k0 + (size_t)64 * K, asD + 64 * 32);
    gl_lds16(bG + k0, bsD);
    gl_lds16(bG + k0 + (size_t)64 * K, bsD + 64 * 32);
    __syncthreads();
    bf16x8 af[4], bfr[4];
#pragma unroll
    for (int i = 0; i < 4; ++i)
      af[i] = *(const bf16x8*)&As[(wm + i * 16 + lr) * 32 + lg * 8];
#pragma unroll
    for (int i = 0; i < 4; ++i)
      bfr[i] = *(const bf16x8*)&Bs[(wn + i * 16 + lr) * 32 + lg * 8];
#pragma unroll
    for (int mi = 0; mi < 4; ++mi)
#pragma unroll
      for (int ni = 0; ni < 4; ++ni)
        acc[mi][ni] = __builtin_amdgcn_mfma_f32_16x16x32_bf16(af[mi], bfr[ni], acc[mi][ni], 0, 0, 0);
    __syncthreads();
  }

  const int row0 = bm + wm + lg * 4;
  const int col0 = bn + wn + lr;
  if (c_is_bf16) {
    u16* C = (u16*)Cout;
#pragma unroll
    for (int mi = 0; mi < 4; ++mi)
#pragma unroll
      for (int j = 0; j < 4; ++j) {
        size_t base = (size_t)(row0 + mi * 16 + j) * N + col0;
#pragma unroll
        for (int ni = 0; ni < 4; ++ni)
          C[base + ni * 16] = f2b(acc[mi][ni][j]);
      }
  } else {
    float* C = (float*)Cout;
#pragma unroll
    for (int mi = 0; mi < 4; ++mi)
#pragma unroll
      for (int j = 0; j < 4; ++j) {
        size_t base = (size_t)(row0 + mi * 16 + j) * N + col0;
#pragma unroll
        for (int ni = 0; ni < 4; ++ni)
          C[base + ni * 16] = acc[mi][ni][j];
      }
  }
}

// ---------------- RoPE + reorder to [nh][S][D] ----------------
// one thread per (h, s, i<64): out[i]=a*cos-b*sin, out[i+64]=b*cos+a*sin
__global__ void rope_qk(const u16* __restrict__ qkv, u16* __restrict__ dst,
                        int col_off, float scale) {
  int idx = blockIdx.x * blockDim.x + threadIdx.x;
  int i = idx & 63;
  int s = (idx >> 6) & (S_LEN - 1);
  int h = idx >> 17;
  const u16* row = qkv + (size_t)s * QKVN + col_off + h * HD;
  float a = b2f(row[i]);
  float b = b2f(row[i + 64]);
  float invf = __expf(-(float)i * 0.14391156831212787f);  // ln(10000)/64
  float f = (float)s * invf;
  float sn, cs;
  sincosf(f, &sn, &cs);
  float o1 = (a * cs - b * sn) * scale;
  float o2 = (b * cs + a * sn) * scale;
  u16* orow = dst + ((size_t)h * S_LEN + s) * HD;
  orow[i]      = f2b(o1);
  orow[i + 64] = f2b(o2);
}

// ---------------- V transpose: qkv[s][5120 + c] -> vt[c][s]  (c = kv*128+d) --
__global__ void v_transpose(const u16* __restrict__ qkv, u16* __restrict__ vt) {
  __shared__ u16 tile[32][33];
  int c0 = blockIdx.x * 32;
  int s0 = blockIdx.y * 32;
  int tx = threadIdx.x, ty = threadIdx.y;
  tile[ty][tx] = qkv[(size_t)(s0 + ty) * QKVN + 5120 + c0 + tx];
  __syncthreads();
  vt[(size_t)(c0 + ty) * S_LEN + s0 + tx] = tile[tx][ty];
}

// ---------------- flash attention (causal, GQA 4:1) ----------------
// grid (S/64, H), block 256. Each wave: 16 q rows, KV tiles of 32 keys.
__global__ __launch_bounds__(256) void attn_fwd(
    const u16* __restrict__ Q,   // [H][S][D]  (already *1/sqrt(D))
    const u16* __restrict__ Kb,  // [KV][S][D]
    const u16* __restrict__ Vt,  // [KV][D][S]
    u16* __restrict__ Out)       // [S][H*D]
{
  __shared__ __align__(16) u16 Pl[4][16 * 32];
  const int tid  = threadIdx.x;
  const int lane = tid & 63;
  const int wv   = tid >> 6;
  const int h    = blockIdx.y;
  const int q0   = (blockIdx.x * 4 + wv) * 16;
  const int kvh  = h >> 2;
  const int lr = lane & 15;
  const int lg = lane >> 4;

  const u16* qp = Q + ((size_t)h * S_LEN + q0) * HD;
  const u16* kp = Kb + (size_t)kvh * S_LEN * HD;
  const u16* vp = Vt + (size_t)kvh * HD * S_LEN;

  bf16x8 qf[4];
#pragma unroll
  for (int kc = 0; kc < 4; ++kc)
    qf[kc] = *(const bf16x8*)&qp[(size_t)lr * HD + kc * 32 + lg * 8];

  f32x4 o[8] = {};
  float m[4]    = {-1e30f, -1e30f, -1e30f, -1e30f};
  float lsum[4] = {0.f, 0.f, 0.f, 0.f};

  const int ntiles = (q0 >> 5) + 1;
  u16* pw = &Pl[wv][0];

  for (int t = 0; t < ntiles; ++t) {
    const int kb = t * 32;
    f32x4 s0 = {}, s1 = {};
#pragma unroll
    for (int kc = 0; kc < 4; ++kc) {
      bf16x8 k0 = *(const bf16x8*)&kp[(size_t)(kb + lr) * HD + kc * 32 + lg * 8];
      s0 = __builtin_amdgcn_mfma_f32_16x16x32_bf16(qf[kc], k0, s0, 0, 0, 0);
    }
#pragma unroll
    for (int kc = 0; kc < 4; ++kc) {
      bf16x8 k1 = *(const bf16x8*)&kp[(size_t)(kb + 16 + lr) * HD + kc * 32 + lg * 8];
      s1 = __builtin_amdgcn_mfma_f32_16x16x32_bf16(qf[kc], k1, s1, 0, 0, 0);
    }
    const bool last = (t == ntiles - 1);
#pragma unroll
    for (int j = 0; j < 4; ++j) {
      float v0 = s0[j], v1 = s1[j];
      if (last) {
        int sq = q0 + lg * 4 + j;
        if (kb + lr > sq)      v0 = -1e30f;
        if (kb + 16 + lr > sq) v1 = -1e30f;
      }
      float vmax = fmaxf(v0, v1);
      vmax = fmaxf(vmax, __shfl_xor(vmax, 1));
      vmax = fmaxf(vmax, __shfl_xor(vmax, 2));
      vmax = fmaxf(vmax, __shfl_xor(vmax, 4));
      vmax = fmaxf(vmax, __shfl_xor(vmax, 8));
      float mn = fmaxf(m[j], vmax);
      float sf = __expf(m[j] - mn);
      m[j] = mn;
      float p0 = __expf(v0 - mn);
      float p1 = __expf(v1 - mn);
      float ps = p0 + p1;
      ps += __shfl_xor(ps, 1);
      ps += __shfl_xor(ps, 2);
      ps += __shfl_xor(ps, 4);
      ps += __shfl_xor(ps, 8);
      lsum[j] = lsum[j] * sf + ps;
      pw[(lg * 4 + j) * 32 + lr]      = f2b(p0);
      pw[(lg * 4 + j) * 32 + 16 + lr] = f2b(p1);
#pragma unroll
      for (int dt = 0; dt < 8; ++dt) o[dt][j] *= sf;
    }
    asm volatile("s_waitcnt lgkmcnt(0)" ::: "memory");
    bf16x8 pa = *(const bf16x8*)&pw[lr * 32 + lg * 8];
#pragma unroll
    for (int dt = 0; dt < 8; ++dt) {
      bf16x8 bv = *(const bf16x8*)&vp[(size_t)(dt * 16 + lr) * S_LEN + kb + lg * 8];
      o[dt] = __builtin_amdgcn_mfma_f32_16x16x32_bf16(pa, bv, o[dt], 0, 0, 0);
    }
  }

#pragma unroll
  for (int j = 0; j < 4; ++j) {
    float inv = 1.0f / lsum[j];
    int s = q0 + lg * 4 + j;
    u16* orow = Out + (size_t)s * (NH * HD) + h * HD;
#pragma unroll
    for (int dt = 0; dt < 8; ++dt)
      orow[dt * 16 + lr] = f2b(o[dt][j] * inv);
  }
}

// ---------------- launcher ----------------
extern "C" void kernel_launch(void* const* d_in, const int* in_sizes, int n_in,
                              void* d_out, int out_size, void* d_ws, size_t ws_size,
                              hipStream_t stream) {
  const float* x  = (const float*)d_in[0];
  const float* Wq = (const float*)d_in[1];
  const float* Wk = (const float*)d_in[2];
  const float* Wv = (const float*)d_in[3];
  const float* Wo = (const float*)d_in[4];
  float* out = (float*)d_out;

  char* ws = (char*)d_ws;
  u16* xb   = (u16*)(ws);                           // [2048][4096]   16 MiB
  u16* wqkv = (u16*)(ws + (16ull << 20));           // [6144][4096]   48 MiB
  u16* wo_b = (u16*)(ws + (64ull << 20));           // [4096][4096]   32 MiB
  u16* qkvb = (u16*)(ws + (96ull << 20));           // [2048][6144]   24 MiB
  // reuse regions that are dead after GEMM1 / before attention:
  u16* qb   = (u16*)(ws + (16ull << 20));           // [32][2048][128] 16 MiB (over wqkv)
  u16* kbuf = (u16*)(ws + (32ull << 20));           // [8][2048][128]   4 MiB
  u16* vt   = (u16*)(ws + (36ull << 20));           // [8][128][2048]   4 MiB
  u16* ao   = (u16*)(ws);                           // [2048][4096]   16 MiB (over xb)

  // casts fp32 -> bf16
  cast_kernel<<<4096, 256, 0, stream>>>(x,  xb,   (2048 * 4096) / 4);
  cast_kernel<<<4096, 256, 0, stream>>>(Wq, wqkv, (4096 * 4096) / 4);
  cast_kernel<<<2048, 256, 0, stream>>>(Wk, wqkv + (size_t)4096 * 4096, (1024 * 4096) / 4);
  cast_kernel<<<2048, 256, 0, stream>>>(Wv, wqkv + (size_t)5120 * 4096, (1024 * 4096) / 4);
  cast_kernel<<<4096, 256, 0, stream>>>(Wo, wo_b, (4096 * 4096) / 4);

  // fused QKV projection: [2048,6144] = x @ [Wq;Wk;Wv]^T
  gemm_bt<<<dim3(48, 16), 256, 0, stream>>>(xb, wqkv, qkvb, 2048, 6144, 4096, 1);

  // RoPE (+ fold 1/sqrt(D) into q) and layout change
  rope_qk<<<(32 * 2048 * 64) / 256, 256, 0, stream>>>(qkvb, qb,   0,    0.08838834764831845f);
  rope_qk<<<(8  * 2048 * 64) / 256, 256, 0, stream>>>(qkvb, kbuf, 4096, 1.0f);
  v_transpose<<<dim3(32, 64), dim3(32, 32), 0, stream>>>(qkvb, vt);

  // causal GQA flash attention
  attn_fwd<<<dim3(32, 32), 256, 0, stream>>>(qb, kbuf, vt, ao);

  // output projection -> fp32 d_out
  gemm_bt<<<dim3(32, 16), 256, 0, stream>>>(ao, wo_b, out, 2048, 4096, 4096, 0);
}

// Round 2
// 453.540 us; speedup vs baseline: 1.6968x; 1.6968x over previous
//
#include <hip/hip_runtime.h>

typedef unsigned short u16;
typedef unsigned int u32;

using f32x4  = __attribute__((ext_vector_type(4))) float;
using f32x16 = __attribute__((ext_vector_type(16))) float;
using bf16x8 = __attribute__((ext_vector_type(8))) __bf16;

#define S_LEN 2048
#define HID_DIM 4096
#define NH 32
#define NKV 8
#define HD 128
#define QKVN 6144

__device__ __forceinline__ u16 f2b(float f) {
  union { float f; u32 u; } v; v.f = f;
  u32 r = (v.u + 0x7FFFu + ((v.u >> 16) & 1u)) >> 16;
  return (u16)r;
}
__device__ __forceinline__ float b2f(u16 b) {
  union { u32 u; float f; } v; v.u = ((u32)b) << 16;
  return v.f;
}

__device__ __forceinline__ u32 cvtpk_bf16(float lo, float hi) {
  u32 r;
  asm("v_cvt_pk_bf16_f32 %0, %1, %2" : "=v"(r) : "v"(lo), "v"(hi));
  return r;
}
// After: a = {a.lo, b.lo}, b = {a.hi, b.hi}  (lanes 0-31 / 32-63 halves)
__device__ __forceinline__ void plane_swap(u32& a, u32& b) {
  asm volatile("v_permlane32_swap_b32 %0, %1" : "+v"(a), "+v"(b));
}

#define AS1 __attribute__((address_space(1)))
#define AS3 __attribute__((address_space(3)))
__device__ __forceinline__ void gl_lds16(const u16* g, u16* l) {
  __builtin_amdgcn_global_load_lds((const AS1 u32*)g, (AS3 u32*)l, 16, 0, 0);
}

// ---------------- fp32 -> bf16 cast (vectorized, grid-stride) ----------------
__global__ void cast_kernel(const float* __restrict__ src, u16* __restrict__ dst, int n4) {
  int i = blockIdx.x * blockDim.x + threadIdx.x;
  int stride = gridDim.x * blockDim.x;
  for (; i < n4; i += stride) {
    float4 v = ((const float4*)src)[i];
    uint2 o;
    o.x = (u32)f2b(v.x) | ((u32)f2b(v.y) << 16);
    o.y = (u32)f2b(v.z) | ((u32)f2b(v.w) << 16);
    ((uint2*)dst)[i] = o;
  }
}

// ---------------- GEMM: C[M,N] = A[M,K] * B[N,K]^T  (bf16 in, f32 acc) -------
__global__ __launch_bounds__(256) void gemm_bt(
    const u16* __restrict__ A, const u16* __restrict__ B, void* __restrict__ Cout,
    int M, int N, int K, int c_is_bf16)
{
  __shared__ __align__(16) u16 As[128 * 32];
  __shared__ __align__(16) u16 Bs[128 * 32];
  const int tid  = threadIdx.x;
  const int lane = tid & 63;
  const int wave = tid >> 6;
  const int bn = blockIdx.x * 128;
  const int bm = blockIdx.y * 128;
  const int wm = (wave >> 1) * 64;
  const int wn = (wave & 1) * 64;
  const int lr = lane & 15;
  const int lg = lane >> 4;

  f32x4 acc[4][4] = {};

  const int r = tid >> 2;
  const u16* aG = A + (size_t)(bm + r) * K + (tid & 3) * 8;
  const u16* bG = B + (size_t)(bn + r) * K + (tid & 3) * 8;
  u16* asD = As + tid * 8;
  u16* bsD = Bs + tid * 8;

  for (int k0 = 0; k0 < K; k0 += 32) {
    gl_lds16(aG + k0, asD);
    gl_lds16(aG + k0 + (size_t)64 * K, asD + 64 * 32);
    gl_lds16(bG + k0, bsD);
    gl_lds16(bG + k0 + (size_t)64 * K, bsD + 64 * 32);
    __syncthreads();
    bf16x8 af[4], bfr[4];
#pragma unroll
    for (int i = 0; i < 4; ++i)
      af[i] = *(const bf16x8*)&As[(wm + i * 16 + lr) * 32 + lg * 8];
#pragma unroll
    for (int i = 0; i < 4; ++i)
      bfr[i] = *(const bf16x8*)&Bs[(wn + i * 16 + lr) * 32 + lg * 8];
#pragma unroll
    for (int mi = 0; mi < 4; ++mi)
#pragma unroll
      for (int ni = 0; ni < 4; ++ni)
        acc[mi][ni] = __builtin_amdgcn_mfma_f32_16x16x32_bf16(af[mi], bfr[ni], acc[mi][ni], 0, 0, 0);
    __syncthreads();
  }

  const int row0 = bm + wm + lg * 4;
  const int col0 = bn + wn + lr;
  if (c_is_bf16) {
    u16* C = (u16*)Cout;
#pragma unroll
    for (int mi = 0; mi < 4; ++mi)
#pragma unroll
      for (int j = 0; j < 4; ++j) {
        size_t base = (size_t)(row0 + mi * 16 + j) * N + col0;
#pragma unroll
        for (int ni = 0; ni < 4; ++ni)
          C[base + ni * 16] = f2b(acc[mi][ni][j]);
      }
  } else {
    float* C = (float*)Cout;
#pragma unroll
    for (int mi = 0; mi < 4; ++mi)
#pragma unroll
      for (int j = 0; j < 4; ++j) {
        size_t base = (size_t)(row0 + mi * 16 + j) * N + col0;
#pragma unroll
        for (int ni = 0; ni < 4; ++ni)
          C[base + ni * 16] = acc[mi][ni][j];
      }
  }
}

// ---------------- RoPE + reorder to [nh][S][D] ----------------
__global__ void rope_qk(const u16* __restrict__ qkv, u16* __restrict__ dst,
                        int col_off, float scale) {
  int idx = blockIdx.x * blockDim.x + threadIdx.x;
  int i = idx & 63;
  int s = (idx >> 6) & (S_LEN - 1);
  int h = idx >> 17;
  const u16* row = qkv + (size_t)s * QKVN + col_off + h * HD;
  float a = b2f(row[i]);
  float b = b2f(row[i + 64]);
  float invf = __expf(-(float)i * 0.14391156831212787f);  // ln(10000)/64
  float f = (float)s * invf;
  float sn, cs;
  sincosf(f, &sn, &cs);
  float o1 = (a * cs - b * sn) * scale;
  float o2 = (b * cs + a * sn) * scale;
  u16* orow = dst + ((size_t)h * S_LEN + s) * HD;
  orow[i]      = f2b(o1);
  orow[i + 64] = f2b(o2);
}

// ---------------- V transpose: qkv[s][5120 + c] -> vt[c][s] ----------------
__global__ void v_transpose(const u16* __restrict__ qkv, u16* __restrict__ vt) {
  __shared__ u16 tile[32][33];
  int c0 = blockIdx.x * 32;
  int s0 = blockIdx.y * 32;
  int tx = threadIdx.x, ty = threadIdx.y;
  tile[ty][tx] = qkv[(size_t)(s0 + ty) * QKVN + 5120 + c0 + tx];
  __syncthreads();
  vt[(size_t)(c0 + ty) * S_LEN + s0 + tx] = tile[tx][ty];
}

// ---------------- flash attention v2: swapped QK^T, in-register softmax ------
// 1 wave per block, 32 q rows per wave, 32-key tiles, mfma 32x32x16.
// S^T[k][q]: q = lane&31, k = (reg&3) + 8*(reg>>2) + 4*(lane>>5)  (+ lane^32 half)
__global__ __launch_bounds__(64, 2) void attn_fwd(
    const u16* __restrict__ Q,   // [H][S][D]  (pre-scaled by 1/sqrt(D))
    const u16* __restrict__ Kb,  // [KV][S][D]
    const u16* __restrict__ Vt,  // [KV][D][S]
    u16* __restrict__ Out)       // [S][H*D]
{
  const int lane = threadIdx.x;
  const int q31  = lane & 31;
  const int hi   = lane >> 5;
  const int b    = blockIdx.x;
  const int h    = b & 31;
  const int qi   = (S_LEN / 32 - 1) - (b >> 5);   // reversed: longest blocks first
  const int q0   = qi * 32;
  const int kvh  = h >> 2;

  const u16* qp = Q  + ((size_t)h * S_LEN + q0) * HD;
  const u16* kp = Kb + (size_t)kvh * S_LEN * HD;
  const u16* vp = Vt + (size_t)kvh * HD * S_LEN;

  // Q fragments (B-operand): qf[dc] = Q[q0+q31][dc*16 + hi*8 + e]
  bf16x8 qf[8];
#pragma unroll
  for (int dc = 0; dc < 8; ++dc)
    qf[dc] = *(const bf16x8*)&qp[(size_t)q31 * HD + dc * 16 + hi * 8];

  f32x16 o0 = {}, o1 = {}, o2 = {}, o3 = {};
  float m = -1e30f, lsum = 0.f;

  const int ntiles = (q0 >> 5) + 1;

  for (int t = 0; t < ntiles; ++t) {
    const int kb = t * 32;

    // V fragments (A-operand for PV): vf[dt*2+kc] = V^T[dt*32+q31][kb+kc*16+hi*8+e]
    bf16x8 vf[8];
#pragma unroll
    for (int i = 0; i < 8; ++i) {
      int dt = i >> 1, kc = i & 1;
      vf[i] = *(const bf16x8*)&vp[(size_t)(dt * 32 + q31) * S_LEN + kb + kc * 16 + hi * 8];
    }

    // QK^T (swapped): st[k][q]
    f32x16 st = {};
#pragma unroll
    for (int dc = 0; dc < 8; ++dc) {
      bf16x8 kf = *(const bf16x8*)&kp[(size_t)(kb + q31) * HD + dc * 16 + hi * 8];
      st = __builtin_amdgcn_mfma_f32_32x32x16_bf16(kf, qf[dc], st, 0, 0, 0);
    }

    // causal mask on diagonal tile (kb == q0 there)
    if (t == ntiles - 1) {
#pragma unroll
      for (int r = 0; r < 16; ++r) {
        int kk = (r & 3) + 8 * (r >> 2) + 4 * hi;
        if (kk > q31) st[r] = -1e30f;
      }
    }

    // row max (k spread over 16 regs x lane^32)
    float pmax = st[0];
#pragma unroll
    for (int r = 1; r < 16; ++r) pmax = fmaxf(pmax, st[r]);
    pmax = fmaxf(pmax, __shfl_xor(pmax, 32));

    // defer-max: rescale only when the running max grows by > 8
    if (__any(pmax > m + 8.f)) {
      float mn = fmaxf(m, pmax);
      float sf = __expf(m - mn);
      m = mn;
      lsum *= sf;
#pragma unroll
      for (int r = 0; r < 16; ++r) { o0[r] *= sf; o1[r] *= sf; o2[r] *= sf; o3[r] *= sf; }
    }

    // p = exp(s - m), row sum
    float ev[16];
    float ps = 0.f;
#pragma unroll
    for (int r = 0; r < 16; ++r) { ev[r] = __expf(st[r] - m); ps += ev[r]; }
    ps += __shfl_xor(ps, 32);
    lsum += ps;

    // pack P to bf16 fragments in-register (cvt_pk + permlane32_swap)
    u32 c0 = cvtpk_bf16(ev[0],  ev[1]),  c1 = cvtpk_bf16(ev[2],  ev[3]);
    u32 c2 = cvtpk_bf16(ev[4],  ev[5]),  c3 = cvtpk_bf16(ev[6],  ev[7]);
    u32 c4 = cvtpk_bf16(ev[8],  ev[9]),  c5 = cvtpk_bf16(ev[10], ev[11]);
    u32 c6 = cvtpk_bf16(ev[12], ev[13]), c7 = cvtpk_bf16(ev[14], ev[15]);
    plane_swap(c0, c2);  // c0 = pb0.w0, c2 = pb0.w2
    plane_swap(c1, c3);  // c1 = pb0.w1, c3 = pb0.w3
    plane_swap(c4, c6);
    plane_swap(c5, c7);
    union { u32 u[4]; bf16x8 v; } pb0u, pb1u;
    pb0u.u[0] = c0; pb0u.u[1] = c1; pb0u.u[2] = c2; pb0u.u[3] = c3;
    pb1u.u[0] = c4; pb1u.u[1] = c5; pb1u.u[2] = c6; pb1u.u[3] = c7;

    // PV: O^T[d][q] += V^T[d][k] * P[q][k]
    o0 = __builtin_amdgcn_mfma_f32_32x32x16_bf16(vf[0], pb0u.v, o0, 0, 0, 0);
    o0 = __builtin_amdgcn_mfma_f32_32x32x16_bf16(vf[1], pb1u.v, o0, 0, 0, 0);
    o1 = __builtin_amdgcn_mfma_f32_32x32x16_bf16(vf[2], pb0u.v, o1, 0, 0, 0);
    o1 = __builtin_amdgcn_mfma_f32_32x32x16_bf16(vf[3], pb1u.v, o1, 0, 0, 0);
    o2 = __builtin_amdgcn_mfma_f32_32x32x16_bf16(vf[4], pb0u.v, o2, 0, 0, 0);
    o2 = __builtin_amdgcn_mfma_f32_32x32x16_bf16(vf[5], pb1u.v, o2, 0, 0, 0);
    o3 = __builtin_amdgcn_mfma_f32_32x32x16_bf16(vf[6], pb0u.v, o3, 0, 0, 0);
    o3 = __builtin_amdgcn_mfma_f32_32x32x16_bf16(vf[7], pb1u.v, o3, 0, 0, 0);
  }

  // epilogue: normalize, pack 4 consecutive d per store
  float inv = 1.0f / lsum;
  u16* orow = Out + (size_t)(q0 + q31) * (NH * HD) + h * HD;
#pragma unroll
  for (int dt = 0; dt < 4; ++dt) {
    const f32x16& oo = dt == 0 ? o0 : dt == 1 ? o1 : dt == 2 ? o2 : o3;
#pragma unroll
    for (int g = 0; g < 4; ++g) {
      ushort4 pk;
      pk.x = f2b(oo[g * 4 + 0] * inv);
      pk.y = f2b(oo[g * 4 + 1] * inv);
      pk.z = f2b(oo[g * 4 + 2] * inv);
      pk.w = f2b(oo[g * 4 + 3] * inv);
      *(ushort4*)&orow[dt * 32 + 8 * g + 4 * hi] = pk;
    }
  }
}

// ---------------- launcher ----------------
extern "C" void kernel_launch(void* const* d_in, const int* in_sizes, int n_in,
                              void* d_out, int out_size, void* d_ws, size_t ws_size,
                              hipStream_t stream) {
  const float* x  = (const float*)d_in[0];
  const float* Wq = (const float*)d_in[1];
  const float* Wk = (const float*)d_in[2];
  const float* Wv = (const float*)d_in[3];
  const float* Wo = (const float*)d_in[4];
  float* out = (float*)d_out;

  char* ws = (char*)d_ws;
  u16* xb   = (u16*)(ws);                           // [2048][4096]   16 MiB
  u16* wqkv = (u16*)(ws + (16ull << 20));           // [6144][4096]   48 MiB
  u16* wo_b = (u16*)(ws + (64ull << 20));           // [4096][4096]   32 MiB
  u16* qkvb = (u16*)(ws + (96ull << 20));           // [2048][6144]   24 MiB
  u16* qb   = (u16*)(ws + (16ull << 20));           // [32][2048][128] 16 MiB (over wqkv)
  u16* kbuf = (u16*)(ws + (32ull << 20));           // [8][2048][128]   4 MiB
  u16* vt   = (u16*)(ws + (36ull << 20));           // [8][128][2048]   4 MiB
  u16* ao   = (u16*)(ws);                           // [2048][4096]   16 MiB (over xb)

  cast_kernel<<<4096, 256, 0, stream>>>(x,  xb,   (2048 * 4096) / 4);
  cast_kernel<<<4096, 256, 0, stream>>>(Wq, wqkv, (4096 * 4096) / 4);
  cast_kernel<<<2048, 256, 0, stream>>>(Wk, wqkv + (size_t)4096 * 4096, (1024 * 4096) / 4);
  cast_kernel<<<2048, 256, 0, stream>>>(Wv, wqkv + (size_t)5120 * 4096, (1024 * 4096) / 4);
  cast_kernel<<<4096, 256, 0, stream>>>(Wo, wo_b, (4096 * 4096) / 4);

  gemm_bt<<<dim3(48, 16), 256, 0, stream>>>(xb, wqkv, qkvb, 2048, 6144, 4096, 1);

  rope_qk<<<(32 * 2048 * 64) / 256, 256, 0, stream>>>(qkvb, qb,   0,    0.08838834764831845f);
  rope_qk<<<(8  * 2048 * 64) / 256, 256, 0, stream>>>(qkvb, kbuf, 4096, 1.0f);
  v_transpose<<<dim3(32, 64), dim3(32, 32), 0, stream>>>(qkvb, vt);

  attn_fwd<<<dim3(2048), 64, 0, stream>>>(qb, kbuf, vt, ao);

  gemm_bt<<<dim3(32, 16), 256, 0, stream>>>(ao, wo_b, out, 2048, 4096, 4096, 0);
}

// Round 3
// 394.989 us; speedup vs baseline: 1.9483x; 1.1482x over previous
//
#include <hip/hip_runtime.h>

typedef unsigned short u16;
typedef unsigned int u32;

using f32x4  = __attribute__((ext_vector_type(4))) float;
using f32x16 = __attribute__((ext_vector_type(16))) float;
using bf16x8 = __attribute__((ext_vector_type(8))) __bf16;

#define S_LEN 2048
#define HID_DIM 4096
#define NH 32
#define NKV 8
#define HD 128
#define QKVN 6144

__device__ __forceinline__ u16 f2b(float f) {
  union { float f; u32 u; } v; v.f = f;
  u32 r = (v.u + 0x7FFFu + ((v.u >> 16) & 1u)) >> 16;
  return (u16)r;
}
__device__ __forceinline__ float b2f(u16 b) {
  union { u32 u; float f; } v; v.u = ((u32)b) << 16;
  return v.f;
}

__device__ __forceinline__ u32 cvtpk_bf16(float lo, float hi) {
  u32 r;
  asm("v_cvt_pk_bf16_f32 %0, %1, %2" : "=v"(r) : "v"(lo), "v"(hi));
  return r;
}
__device__ __forceinline__ void plane_swap(u32& a, u32& b) {
  asm volatile("v_permlane32_swap_b32 %0, %1" : "+v"(a), "+v"(b));
}

#define AS1 __attribute__((address_space(1)))
#define AS3 __attribute__((address_space(3)))
__device__ __forceinline__ void gl_lds16(const u16* g, u16* l) {
  __builtin_amdgcn_global_load_lds((const AS1 u32*)g, (AS3 u32*)l, 16, 0, 0);
}

#define SBAR  __builtin_amdgcn_s_barrier()
#define SCHED0 __builtin_amdgcn_sched_barrier(0)
#define LGKM0 do { asm volatile("s_waitcnt lgkmcnt(0)" ::: "memory"); SCHED0; } while (0)
#define PRIO1 __builtin_amdgcn_s_setprio(1)
#define PRIO0 __builtin_amdgcn_s_setprio(0)

template <int N> __device__ __forceinline__ void waitv() {
  if constexpr (N == 0) asm volatile("s_waitcnt vmcnt(0)" ::: "memory");
  else if constexpr (N == 6) asm volatile("s_waitcnt vmcnt(6)" ::: "memory");
  else if constexpr (N == 7) asm volatile("s_waitcnt vmcnt(7)" ::: "memory");
  else asm volatile("s_waitcnt vmcnt(0)" ::: "memory");
  SCHED0;
}

// ---------------- fp32 -> bf16 cast ----------------
__global__ void cast_kernel(const float* __restrict__ src, u16* __restrict__ dst, int n4) {
  int i = blockIdx.x * blockDim.x + threadIdx.x;
  int stride = gridDim.x * blockDim.x;
  for (; i < n4; i += stride) {
    float4 v = ((const float4*)src)[i];
    uint2 o;
    o.x = (u32)f2b(v.x) | ((u32)f2b(v.y) << 16);
    o.y = (u32)f2b(v.z) | ((u32)f2b(v.w) << 16);
    ((uint2*)dst)[i] = o;
  }
}

// ============ 8-phase 256-wide GEMM: C[M,N] = A[M,K] * B[N,K]^T ============
// BM=256 fixed, BK=64, 512 threads = 8 waves (2 m-groups x 4 n-groups).
// Per-wave output: 128 x WN  (MF=8 m-frags, NF=WN/16 n-frags).
// LDS: double-buffered A[256][64] + B[BN][64] bf16, XOR-swizzled
//   (byte_in_row ^= (row&7)<<4), swizzle applied on BOTH the pre-swizzled
//   global_load_lds source address and the ds_read address (linear LDS dest).
// Schedule per K-tile (4 phases, raw s_barrier, counted vmcnt once per tile):
//   P0: ds_read A[m0..3][ks01] + B[ks0];  MFMA m0..3 x ks0
//   P1: ds_read A[m4..7][ks01] + B[ks1];  MFMA m4..7 x ks0
//   P2: stage A(t+2);                     MFMA m0..3 x ks1
//   P3: stage B(t+2); vmcnt(L);           MFMA m4..7 x ks1

#define STAGE(DST, SRC, CH, LDK)                                   \
  _Pragma("unroll") for (int c = 0; c < (CH); ++c) {               \
    int d_ = c * 8192 + tid * 16;                                  \
    int rw_ = d_ >> 7;                                             \
    int cb_ = (d_ & 127) ^ ((rw_ & 7) << 4);                       \
    gl_lds16((SRC) + (size_t)rw_ * (LDK) + (cb_ >> 1), (DST) + (d_ >> 1)); \
  }

#define READ_A(ABUF, MLO)                                                     \
  _Pragma("unroll") for (int mm = 0; mm < 4; ++mm)                            \
  _Pragma("unroll") for (int ks = 0; ks < 2; ++ks)                            \
    af[(MLO) + mm][ks] = *(const bf16x8*)((const char*)(ABUF) +               \
      (wmo + ((MLO) + mm) * 16 + lr) * 128 + ((((ks << 2) | lg) ^ lr7) << 4));

#define READ_B(BBUF, KS)                                                      \
  _Pragma("unroll") for (int nn = 0; nn < NF; ++nn)                           \
    bfr[nn][KS] = *(const bf16x8*)((const char*)(BBUF) +                      \
      (wno + nn * 16 + lr) * 128 + (((((KS) << 2) | lg) ^ lr7) << 4));

#define MFMA_Q(MLO, KS)                                                       \
  _Pragma("unroll") for (int mm = 0; mm < 4; ++mm)                            \
  _Pragma("unroll") for (int nn = 0; nn < NF; ++nn)                           \
    acc[(MLO) + mm][nn] = __builtin_amdgcn_mfma_f32_16x16x32_bf16(            \
        af[(MLO) + mm][KS], bfr[nn][KS], acc[(MLO) + mm][nn], 0, 0, 0);

template <int BN, int WN, int CBF>
__global__ __launch_bounds__(512, 2) void gemm8p(
    const u16* __restrict__ A, const u16* __restrict__ B, void* __restrict__ Cout,
    int M, int N, int K)
{
  constexpr int BM = 256;
  constexpr int NF = WN / 16;
  constexpr int LA = BM / 64;       // 4 gl_lds per A tile
  constexpr int LB = BN / 64;       // 3 or 2 per B tile
  constexpr int LT = LA + LB;       // loads per K-tile
  extern __shared__ __align__(16) u16 smem[];
  // layout: A0 | A1 | B0 | B1   (u16 offsets)
  u16* const As0 = smem;
  u16* const Bs0 = smem + 2 * BM * 64;

  const int tid  = threadIdx.x;
  const int lane = tid & 63;
  const int wave = tid >> 6;
  const int lr  = lane & 15;
  const int lg  = lane >> 4;
  const int lr7 = lane & 7;

  const int nbx = N / BN;
  const int bid = blockIdx.x;
  const int cpx = gridDim.x >> 3;
  const int swz = (bid & 7) * cpx + (bid >> 3);   // XCD swizzle (grid%8==0)
  const int bm = (swz / nbx) * BM;
  const int bn = (swz % nbx) * BN;
  const int wmo = (wave >> 2) * 128;
  const int wno = (wave & 3) * WN;

  const int NT = K >> 6;

  f32x4 acc[8][NF] = {};
  bf16x8 af[8][2], bfr[NF][2];

  const u16* aP = A + (size_t)bm * K;
  const u16* bP = B + (size_t)bn * K;

  // prologue: stage tiles 0 and 1
  STAGE(As0,               aP,      LA, K);
  STAGE(Bs0,               bP,      LB, K);
  STAGE(As0 + BM * 64,     aP + 64, LA, K);
  STAGE(Bs0 + BN * 64,     bP + 64, LB, K);
  waitv<LT>();          // tile0 resident, tile1's LT loads in flight
  SBAR; SCHED0;

  for (int t = 0; t < NT; ++t) {
    const int buf = t & 1;
    const u16* ab = As0 + buf * (BM * 64);
    const u16* bb = Bs0 + buf * (BN * 64);
    const bool st = (t + 2 < NT);

    // ---- P0 ----
    READ_A(ab, 0);
    READ_B(bb, 0);
    SCHED0; SBAR; LGKM0;
    PRIO1; MFMA_Q(0, 0); PRIO0;
    SBAR; SCHED0;

    // ---- P1 ----
    READ_A(ab, 4);
    READ_B(bb, 1);
    SCHED0; SBAR; LGKM0;
    PRIO1; MFMA_Q(4, 0); PRIO0;
    SBAR; SCHED0;

    // ---- P2 ----  (all reads of this buffer drained at P1's barrier)
    if (st) {
      const u16* aS = aP + (size_t)(t + 2) * 64;
      u16* aD = As0 + buf * (BM * 64);
      STAGE(aD, aS, LA, K);
    }
    SCHED0; SBAR;
    PRIO1; MFMA_Q(0, 1); PRIO0;
    SBAR; SCHED0;

    // ---- P3 ----
    if (st) {
      const u16* bS = bP + (size_t)(t + 2) * 64;
      u16* bD = Bs0 + buf * (BN * 64);
      STAGE(bD, bS, LB, K);
    }
    SCHED0; SBAR;
    PRIO1; MFMA_Q(4, 1); PRIO0;
    if (t + 1 < NT) {
      if (t < NT - 3) waitv<LT>(); else waitv<0>();
    }
    SBAR; SCHED0;
  }

  // epilogue
#pragma unroll
  for (int m = 0; m < 8; ++m)
#pragma unroll
    for (int j = 0; j < 4; ++j) {
      int row = bm + wmo + m * 16 + lg * 4 + j;
      size_t base = (size_t)row * N + bn + wno + lr;
      if constexpr (CBF) {
        u16* C = (u16*)Cout;
#pragma unroll
        for (int nn = 0; nn < NF; ++nn) C[base + nn * 16] = f2b(acc[m][nn][j]);
      } else {
        float* C = (float*)Cout;
#pragma unroll
        for (int nn = 0; nn < NF; ++nn) C[base + nn * 16] = acc[m][nn][j];
      }
    }
}

// ---------------- RoPE + reorder to [nh][S][D] ----------------
__global__ void rope_qk(const u16* __restrict__ qkv, u16* __restrict__ dst,
                        int col_off, float scale) {
  int idx = blockIdx.x * blockDim.x + threadIdx.x;
  int i = idx & 63;
  int s = (idx >> 6) & (S_LEN - 1);
  int h = idx >> 17;
  const u16* row = qkv + (size_t)s * QKVN + col_off + h * HD;
  float a = b2f(row[i]);
  float b = b2f(row[i + 64]);
  float invf = __expf(-(float)i * 0.14391156831212787f);  // ln(10000)/64
  float f = (float)s * invf;
  float sn, cs;
  sincosf(f, &sn, &cs);
  float o1 = (a * cs - b * sn) * scale;
  float o2 = (b * cs + a * sn) * scale;
  u16* orow = dst + ((size_t)h * S_LEN + s) * HD;
  orow[i]      = f2b(o1);
  orow[i + 64] = f2b(o2);
}

// ---------------- V transpose: qkv[s][5120 + c] -> vt[c][s] ----------------
__global__ void v_transpose(const u16* __restrict__ qkv, u16* __restrict__ vt) {
  __shared__ u16 tile[32][33];
  int c0 = blockIdx.x * 32;
  int s0 = blockIdx.y * 32;
  int tx = threadIdx.x, ty = threadIdx.y;
  tile[ty][tx] = qkv[(size_t)(s0 + ty) * QKVN + 5120 + c0 + tx];
  __syncthreads();
  vt[(size_t)(c0 + ty) * S_LEN + s0 + tx] = tile[tx][ty];
}

// ---------------- flash attention: swapped QK^T, in-register softmax ------
__global__ __launch_bounds__(64, 2) void attn_fwd(
    const u16* __restrict__ Q,   // [H][S][D]  (pre-scaled by 1/sqrt(D))
    const u16* __restrict__ Kb,  // [KV][S][D]
    const u16* __restrict__ Vt,  // [KV][D][S]
    u16* __restrict__ Out)       // [S][H*D]
{
  const int lane = threadIdx.x;
  const int q31  = lane & 31;
  const int hi   = lane >> 5;
  const int b    = blockIdx.x;
  const int h    = b & 31;
  const int qi   = (S_LEN / 32 - 1) - (b >> 5);
  const int q0   = qi * 32;
  const int kvh  = h >> 2;

  const u16* qp = Q  + ((size_t)h * S_LEN + q0) * HD;
  const u16* kp = Kb + (size_t)kvh * S_LEN * HD;
  const u16* vp = Vt + (size_t)kvh * HD * S_LEN;

  bf16x8 qf[8];
#pragma unroll
  for (int dc = 0; dc < 8; ++dc)
    qf[dc] = *(const bf16x8*)&qp[(size_t)q31 * HD + dc * 16 + hi * 8];

  f32x16 o0 = {}, o1 = {}, o2 = {}, o3 = {};
  float m = -1e30f, lsum = 0.f;

  const int ntiles = (q0 >> 5) + 1;

  for (int t = 0; t < ntiles; ++t) {
    const int kb = t * 32;

    bf16x8 vf[8];
#pragma unroll
    for (int i = 0; i < 8; ++i) {
      int dt = i >> 1, kc = i & 1;
      vf[i] = *(const bf16x8*)&vp[(size_t)(dt * 32 + q31) * S_LEN + kb + kc * 16 + hi * 8];
    }

    f32x16 st = {};
#pragma unroll
    for (int dc = 0; dc < 8; ++dc) {
      bf16x8 kf = *(const bf16x8*)&kp[(size_t)(kb + q31) * HD + dc * 16 + hi * 8];
      st = __builtin_amdgcn_mfma_f32_32x32x16_bf16(kf, qf[dc], st, 0, 0, 0);
    }

    if (t == ntiles - 1) {
#pragma unroll
      for (int r = 0; r < 16; ++r) {
        int kk = (r & 3) + 8 * (r >> 2) + 4 * hi;
        if (kk > q31) st[r] = -1e30f;
      }
    }

    float pmax = st[0];
#pragma unroll
    for (int r = 1; r < 16; ++r) pmax = fmaxf(pmax, st[r]);
    pmax = fmaxf(pmax, __shfl_xor(pmax, 32));

    if (__any(pmax > m + 8.f)) {
      float mn = fmaxf(m, pmax);
      float sf = __expf(m - mn);
      m = mn;
      lsum *= sf;
#pragma unroll
      for (int r = 0; r < 16; ++r) { o0[r] *= sf; o1[r] *= sf; o2[r] *= sf; o3[r] *= sf; }
    }

    float ev[16];
    float ps = 0.f;
#pragma unroll
    for (int r = 0; r < 16; ++r) { ev[r] = __expf(st[r] - m); ps += ev[r]; }
    ps += __shfl_xor(ps, 32);
    lsum += ps;

    u32 c0 = cvtpk_bf16(ev[0],  ev[1]),  c1 = cvtpk_bf16(ev[2],  ev[3]);
    u32 c2 = cvtpk_bf16(ev[4],  ev[5]),  c3 = cvtpk_bf16(ev[6],  ev[7]);
    u32 c4 = cvtpk_bf16(ev[8],  ev[9]),  c5 = cvtpk_bf16(ev[10], ev[11]);
    u32 c6 = cvtpk_bf16(ev[12], ev[13]), c7 = cvtpk_bf16(ev[14], ev[15]);
    plane_swap(c0, c2);
    plane_swap(c1, c3);
    plane_swap(c4, c6);
    plane_swap(c5, c7);
    union { u32 u[4]; bf16x8 v; } pb0u, pb1u;
    pb0u.u[0] = c0; pb0u.u[1] = c1; pb0u.u[2] = c2; pb0u.u[3] = c3;
    pb1u.u[0] = c4; pb1u.u[1] = c5; pb1u.u[2] = c6; pb1u.u[3] = c7;

    o0 = __builtin_amdgcn_mfma_f32_32x32x16_bf16(vf[0], pb0u.v, o0, 0, 0, 0);
    o0 = __builtin_amdgcn_mfma_f32_32x32x16_bf16(vf[1], pb1u.v, o0, 0, 0, 0);
    o1 = __builtin_amdgcn_mfma_f32_32x32x16_bf16(vf[2], pb0u.v, o1, 0, 0, 0);
    o1 = __builtin_amdgcn_mfma_f32_32x32x16_bf16(vf[3], pb1u.v, o1, 0, 0, 0);
    o2 = __builtin_amdgcn_mfma_f32_32x32x16_bf16(vf[4], pb0u.v, o2, 0, 0, 0);
    o2 = __builtin_amdgcn_mfma_f32_32x32x16_bf16(vf[5], pb1u.v, o2, 0, 0, 0);
    o3 = __builtin_amdgcn_mfma_f32_32x32x16_bf16(vf[6], pb0u.v, o3, 0, 0, 0);
    o3 = __builtin_amdgcn_mfma_f32_32x32x16_bf16(vf[7], pb1u.v, o3, 0, 0, 0);
  }

  float inv = 1.0f / lsum;
  u16* orow = Out + (size_t)(q0 + q31) * (NH * HD) + h * HD;
#pragma unroll
  for (int dt = 0; dt < 4; ++dt) {
    const f32x16& oo = dt == 0 ? o0 : dt == 1 ? o1 : dt == 2 ? o2 : o3;
#pragma unroll
    for (int g = 0; g < 4; ++g) {
      ushort4 pk;
      pk.x = f2b(oo[g * 4 + 0] * inv);
      pk.y = f2b(oo[g * 4 + 1] * inv);
      pk.z = f2b(oo[g * 4 + 2] * inv);
      pk.w = f2b(oo[g * 4 + 3] * inv);
      *(ushort4*)&orow[dt * 32 + 8 * g + 4 * hi] = pk;
    }
  }
}

// ---------------- launcher ----------------
extern "C" void kernel_launch(void* const* d_in, const int* in_sizes, int n_in,
                              void* d_out, int out_size, void* d_ws, size_t ws_size,
                              hipStream_t stream) {
  const float* x  = (const float*)d_in[0];
  const float* Wq = (const float*)d_in[1];
  const float* Wk = (const float*)d_in[2];
  const float* Wv = (const float*)d_in[3];
  const float* Wo = (const float*)d_in[4];
  float* out = (float*)d_out;

  char* ws = (char*)d_ws;
  u16* xb   = (u16*)(ws);                           // [2048][4096]   16 MiB
  u16* wqkv = (u16*)(ws + (16ull << 20));           // [6144][4096]   48 MiB
  u16* wo_b = (u16*)(ws + (64ull << 20));           // [4096][4096]   32 MiB
  u16* qkvb = (u16*)(ws + (96ull << 20));           // [2048][6144]   24 MiB
  u16* qb   = (u16*)(ws + (16ull << 20));           // [32][2048][128] 16 MiB (over wqkv)
  u16* kbuf = (u16*)(ws + (32ull << 20));           // [8][2048][128]   4 MiB
  u16* vt   = (u16*)(ws + (36ull << 20));           // [8][128][2048]   4 MiB
  u16* ao   = (u16*)(ws);                           // [2048][4096]   16 MiB (over xb)

  const int smem_q = (256 + 192) * 256;  // 114688 B
  const int smem_o = (256 + 128) * 256;  //  98304 B
  hipFuncSetAttribute((const void*)&gemm8p<192, 48, 1>,
                      hipFuncAttributeMaxDynamicSharedMemorySize, smem_q);
  hipFuncSetAttribute((const void*)&gemm8p<128, 32, 0>,
                      hipFuncAttributeMaxDynamicSharedMemorySize, smem_o);

  cast_kernel<<<4096, 256, 0, stream>>>(x,  xb,   (2048 * 4096) / 4);
  cast_kernel<<<4096, 256, 0, stream>>>(Wq, wqkv, (4096 * 4096) / 4);
  cast_kernel<<<2048, 256, 0, stream>>>(Wk, wqkv + (size_t)4096 * 4096, (1024 * 4096) / 4);
  cast_kernel<<<2048, 256, 0, stream>>>(Wv, wqkv + (size_t)5120 * 4096, (1024 * 4096) / 4);
  cast_kernel<<<4096, 256, 0, stream>>>(Wo, wo_b, (4096 * 4096) / 4);

  // fused QKV projection: [2048,6144] = x @ [Wq;Wk;Wv]^T   (256x192 tiles, 256 blocks)
  gemm8p<192, 48, 1><<<256, 512, smem_q, stream>>>(xb, wqkv, qkvb, 2048, 6144, 4096);

  rope_qk<<<(32 * 2048 * 64) / 256, 256, 0, stream>>>(qkvb, qb,   0,    0.08838834764831845f);
  rope_qk<<<(8  * 2048 * 64) / 256, 256, 0, stream>>>(qkvb, kbuf, 4096, 1.0f);
  v_transpose<<<dim3(32, 64), dim3(32, 32), 0, stream>>>(qkvb, vt);

  attn_fwd<<<dim3(2048), 64, 0, stream>>>(qb, kbuf, vt, ao);

  // output projection -> fp32 d_out   (256x128 tiles, 256 blocks)
  gemm8p<128, 32, 0><<<256, 512, smem_o, stream>>>(ao, wo_b, out, 2048, 4096, 4096);
}

// Round 4
// 385.052 us; speedup vs baseline: 1.9986x; 1.0258x over previous
//
#include <hip/hip_runtime.h>

typedef unsigned short u16;
typedef unsigned int u32;

using f32x4  = __attribute__((ext_vector_type(4))) float;
using f32x16 = __attribute__((ext_vector_type(16))) float;
using bf16x8 = __attribute__((ext_vector_type(8))) __bf16;

#define S_LEN 2048
#define HID_DIM 4096
#define NH 32
#define NKV 8
#define HD 128
#define QKVN 6144

__device__ __forceinline__ u16 f2b(float f) {
  union { float f; u32 u; } v; v.f = f;
  u32 r = (v.u + 0x7FFFu + ((v.u >> 16) & 1u)) >> 16;
  return (u16)r;
}
__device__ __forceinline__ float b2f(u16 b) {
  union { u32 u; float f; } v; v.u = ((u32)b) << 16;
  return v.f;
}

__device__ __forceinline__ u32 cvtpk_bf16(float lo, float hi) {
  u32 r;
  asm("v_cvt_pk_bf16_f32 %0, %1, %2" : "=v"(r) : "v"(lo), "v"(hi));
  return r;
}
__device__ __forceinline__ void plane_swap(u32& a, u32& b) {
  asm volatile("v_permlane32_swap_b32 %0, %1" : "+v"(a), "+v"(b));
}

#define AS1 __attribute__((address_space(1)))
#define AS3 __attribute__((address_space(3)))
__device__ __forceinline__ void gl_lds16(const u16* g, u16* l) {
  __builtin_amdgcn_global_load_lds((const AS1 u32*)g, (AS3 u32*)l, 16, 0, 0);
}

#define SBAR  __builtin_amdgcn_s_barrier()
#define SCHED0 __builtin_amdgcn_sched_barrier(0)
#define LGKM0 do { asm volatile("s_waitcnt lgkmcnt(0)" ::: "memory"); SCHED0; } while (0)
#define PRIO1 __builtin_amdgcn_s_setprio(1)
#define PRIO0 __builtin_amdgcn_s_setprio(0)

template <int N> __device__ __forceinline__ void waitv() {
  if constexpr (N == 0) asm volatile("s_waitcnt vmcnt(0)" ::: "memory");
  else if constexpr (N == 6) asm volatile("s_waitcnt vmcnt(6)" ::: "memory");
  else if constexpr (N == 7) asm volatile("s_waitcnt vmcnt(7)" ::: "memory");
  else asm volatile("s_waitcnt vmcnt(0)" ::: "memory");
  SCHED0;
}

// ---------------- fp32 -> bf16 cast ----------------
__global__ void cast_kernel(const float* __restrict__ src, u16* __restrict__ dst, int n4) {
  int i = blockIdx.x * blockDim.x + threadIdx.x;
  int stride = gridDim.x * blockDim.x;
  for (; i < n4; i += stride) {
    float4 v = ((const float4*)src)[i];
    uint2 o;
    o.x = (u32)f2b(v.x) | ((u32)f2b(v.y) << 16);
    o.y = (u32)f2b(v.z) | ((u32)f2b(v.w) << 16);
    ((uint2*)dst)[i] = o;
  }
}

// ============ 8-phase 256-wide GEMM: C[M,N] = A[M,K] * B[N,K]^T ============
#define STAGE(DST, SRC, CH, LDK)                                   \
  _Pragma("unroll") for (int c = 0; c < (CH); ++c) {               \
    int d_ = c * 8192 + tid * 16;                                  \
    int rw_ = d_ >> 7;                                             \
    int cb_ = (d_ & 127) ^ ((rw_ & 7) << 4);                       \
    gl_lds16((SRC) + (size_t)rw_ * (LDK) + (cb_ >> 1), (DST) + (d_ >> 1)); \
  }

#define READ_A(ABUF, MLO)                                                     \
  _Pragma("unroll") for (int mm = 0; mm < 4; ++mm)                            \
  _Pragma("unroll") for (int ks = 0; ks < 2; ++ks)                            \
    af[(MLO) + mm][ks] = *(const bf16x8*)((const char*)(ABUF) +               \
      (wmo + ((MLO) + mm) * 16 + lr) * 128 + ((((ks << 2) | lg) ^ lr7) << 4));

#define READ_B(BBUF, KS)                                                      \
  _Pragma("unroll") for (int nn = 0; nn < NF; ++nn)                           \
    bfr[nn][KS] = *(const bf16x8*)((const char*)(BBUF) +                      \
      (wno + nn * 16 + lr) * 128 + (((((KS) << 2) | lg) ^ lr7) << 4));

#define MFMA_Q(MLO, KS)                                                       \
  _Pragma("unroll") for (int mm = 0; mm < 4; ++mm)                            \
  _Pragma("unroll") for (int nn = 0; nn < NF; ++nn)                           \
    acc[(MLO) + mm][nn] = __builtin_amdgcn_mfma_f32_16x16x32_bf16(            \
        af[(MLO) + mm][KS], bfr[nn][KS], acc[(MLO) + mm][nn], 0, 0, 0);

template <int BN, int WN, int CBF>
__global__ __launch_bounds__(512, 2) void gemm8p(
    const u16* __restrict__ A, const u16* __restrict__ B, void* __restrict__ Cout,
    int M, int N, int K)
{
  constexpr int BM = 256;
  constexpr int NF = WN / 16;
  constexpr int LA = BM / 64;
  constexpr int LB = BN / 64;
  constexpr int LT = LA + LB;
  extern __shared__ __align__(16) u16 smem[];
  u16* const As0 = smem;
  u16* const Bs0 = smem + 2 * BM * 64;

  const int tid  = threadIdx.x;
  const int lane = tid & 63;
  const int wave = tid >> 6;
  const int lr  = lane & 15;
  const int lg  = lane >> 4;
  const int lr7 = lane & 7;

  const int nbx = N / BN;
  const int bid = blockIdx.x;
  const int cpx = gridDim.x >> 3;
  const int swz = (bid & 7) * cpx + (bid >> 3);
  const int bm = (swz / nbx) * BM;
  const int bn = (swz % nbx) * BN;
  const int wmo = (wave >> 2) * 128;
  const int wno = (wave & 3) * WN;

  const int NT = K >> 6;

  f32x4 acc[8][NF] = {};
  bf16x8 af[8][2], bfr[NF][2];

  const u16* aP = A + (size_t)bm * K;
  const u16* bP = B + (size_t)bn * K;

  STAGE(As0,               aP,      LA, K);
  STAGE(Bs0,               bP,      LB, K);
  STAGE(As0 + BM * 64,     aP + 64, LA, K);
  STAGE(Bs0 + BN * 64,     bP + 64, LB, K);
  waitv<LT>();
  SBAR; SCHED0;

  for (int t = 0; t < NT; ++t) {
    const int buf = t & 1;
    const u16* ab = As0 + buf * (BM * 64);
    const u16* bb = Bs0 + buf * (BN * 64);
    const bool st = (t + 2 < NT);

    READ_A(ab, 0);
    READ_B(bb, 0);
    SCHED0; SBAR; LGKM0;
    PRIO1; MFMA_Q(0, 0); PRIO0;
    SBAR; SCHED0;

    READ_A(ab, 4);
    READ_B(bb, 1);
    SCHED0; SBAR; LGKM0;
    PRIO1; MFMA_Q(4, 0); PRIO0;
    SBAR; SCHED0;

    if (st) {
      const u16* aS = aP + (size_t)(t + 2) * 64;
      u16* aD = As0 + buf * (BM * 64);
      STAGE(aD, aS, LA, K);
    }
    SCHED0; SBAR;
    PRIO1; MFMA_Q(0, 1); PRIO0;
    SBAR; SCHED0;

    if (st) {
      const u16* bS = bP + (size_t)(t + 2) * 64;
      u16* bD = Bs0 + buf * (BN * 64);
      STAGE(bD, bS, LB, K);
    }
    SCHED0; SBAR;
    PRIO1; MFMA_Q(4, 1); PRIO0;
    if (t + 1 < NT) {
      if (t < NT - 3) waitv<LT>(); else waitv<0>();
    }
    SBAR; SCHED0;
  }

#pragma unroll
  for (int m = 0; m < 8; ++m)
#pragma unroll
    for (int j = 0; j < 4; ++j) {
      int row = bm + wmo + m * 16 + lg * 4 + j;
      size_t base = (size_t)row * N + bn + wno + lr;
      if constexpr (CBF) {
        u16* C = (u16*)Cout;
#pragma unroll
        for (int nn = 0; nn < NF; ++nn) C[base + nn * 16] = f2b(acc[m][nn][j]);
      } else {
        float* C = (float*)Cout;
#pragma unroll
        for (int nn = 0; nn < NF; ++nn) C[base + nn * 16] = acc[m][nn][j];
      }
    }
}

// ---------------- RoPE + reorder to [nh][S][D] ----------------
__global__ void rope_qk(const u16* __restrict__ qkv, u16* __restrict__ dst,
                        int col_off, float scale) {
  int idx = blockIdx.x * blockDim.x + threadIdx.x;
  int i = idx & 63;
  int s = (idx >> 6) & (S_LEN - 1);
  int h = idx >> 17;
  const u16* row = qkv + (size_t)s * QKVN + col_off + h * HD;
  float a = b2f(row[i]);
  float b = b2f(row[i + 64]);
  float invf = __expf(-(float)i * 0.14391156831212787f);  // ln(10000)/64
  float f = (float)s * invf;
  float sn, cs;
  sincosf(f, &sn, &cs);
  float o1 = (a * cs - b * sn) * scale;
  float o2 = (b * cs + a * sn) * scale;
  u16* orow = dst + ((size_t)h * S_LEN + s) * HD;
  orow[i]      = f2b(o1);
  orow[i + 64] = f2b(o2);
}

// ---------------- V transpose: qkv[s][5120 + c] -> vt[c][s] ----------------
__global__ void v_transpose(const u16* __restrict__ qkv, u16* __restrict__ vt) {
  __shared__ u16 tile[32][33];
  int c0 = blockIdx.x * 32;
  int s0 = blockIdx.y * 32;
  int tx = threadIdx.x, ty = threadIdx.y;
  tile[ty][tx] = qkv[(size_t)(s0 + ty) * QKVN + 5120 + c0 + tx];
  __syncthreads();
  vt[(size_t)(c0 + ty) * S_LEN + s0 + tx] = tile[tx][ty];
}

// ---------------- flash attention v3: K register-prefetch pipeline ----------
// 1 wave/block, 32 q rows, 32-key tiles, swapped QK^T on mfma 32x32x16.
// kA/kB double-buffer: K(t+1) loads issue before tile-t compute (T14).
__global__ __launch_bounds__(64, 2) void attn_fwd(
    const u16* __restrict__ Q,   // [H][S][D]  (pre-scaled by 1/sqrt(D))
    const u16* __restrict__ Kb,  // [KV][S][D]
    const u16* __restrict__ Vt,  // [KV][D][S]
    u16* __restrict__ Out)       // [S][H*D]
{
  const int lane = threadIdx.x;
  const int q31  = lane & 31;
  const int hi   = lane >> 5;
  const int b    = blockIdx.x;
  const int h    = b & 31;
  const int qi   = (S_LEN / 32 - 1) - (b >> 5);   // longest blocks first
  const int q0   = qi * 32;
  const int kvh  = h >> 2;

  const u16* qp = Q  + ((size_t)h * S_LEN + q0) * HD;
  const u16* kp = Kb + (size_t)kvh * S_LEN * HD;
  const u16* vp = Vt + (size_t)kvh * HD * S_LEN;

  bf16x8 qf[8];
#pragma unroll
  for (int dc = 0; dc < 8; ++dc)
    qf[dc] = *(const bf16x8*)&qp[(size_t)q31 * HD + dc * 16 + hi * 8];

  f32x16 o0 = {}, o1 = {}, o2 = {}, o3 = {};
  float m = -1e30f, lsum = 0.f;

  const int ntiles = (q0 >> 5) + 1;

  bf16x8 kA[8], kB[8];

  auto LOADK = [&](bf16x8* kf, int kb) {
#pragma unroll
    for (int dc = 0; dc < 8; ++dc)
      kf[dc] = *(const bf16x8*)&kp[(size_t)(kb + q31) * HD + dc * 16 + hi * 8];
  };
  auto LOADV = [&](bf16x8* vf, int kb) {
#pragma unroll
    for (int i = 0; i < 8; ++i) {
      int dt = i >> 1, kc = i & 1;
      vf[i] = *(const bf16x8*)&vp[(size_t)(dt * 32 + q31) * S_LEN + kb + kc * 16 + hi * 8];
    }
  };

  auto TILE = [&](const bf16x8* kf, const bf16x8* vf, int t) {
    // QK^T (swapped): st[k][q]
    f32x16 st = {};
    PRIO1;
#pragma unroll
    for (int dc = 0; dc < 8; ++dc)
      st = __builtin_amdgcn_mfma_f32_32x32x16_bf16(kf[dc], qf[dc], st, 0, 0, 0);
    PRIO0;

    if (t == ntiles - 1) {
#pragma unroll
      for (int r = 0; r < 16; ++r) {
        int kk = (r & 3) + 8 * (r >> 2) + 4 * hi;
        if (kk > q31) st[r] = -1e30f;
      }
    }

    // row max: tree
    float a0 = fmaxf(st[0], st[1]),   a1 = fmaxf(st[2], st[3]);
    float a2 = fmaxf(st[4], st[5]),   a3 = fmaxf(st[6], st[7]);
    float a4 = fmaxf(st[8], st[9]),   a5 = fmaxf(st[10], st[11]);
    float a6 = fmaxf(st[12], st[13]), a7 = fmaxf(st[14], st[15]);
    a0 = fmaxf(a0, a1); a2 = fmaxf(a2, a3); a4 = fmaxf(a4, a5); a6 = fmaxf(a6, a7);
    float pmax = fmaxf(fmaxf(a0, a2), fmaxf(a4, a6));
    pmax = fmaxf(pmax, __shfl_xor(pmax, 32));

    if (__any(pmax > m + 8.f)) {
      float mn = fmaxf(m, pmax);
      float sf = __expf(m - mn);
      m = mn;
      lsum *= sf;
#pragma unroll
      for (int r = 0; r < 16; ++r) { o0[r] *= sf; o1[r] *= sf; o2[r] *= sf; o3[r] *= sf; }
    }

    float ev[16];
#pragma unroll
    for (int r = 0; r < 16; ++r) ev[r] = __expf(st[r] - m);
    // tree sum
    float s0 = (ev[0] + ev[1]) + (ev[2] + ev[3]);
    float s1 = (ev[4] + ev[5]) + (ev[6] + ev[7]);
    float s2 = (ev[8] + ev[9]) + (ev[10] + ev[11]);
    float s3 = (ev[12] + ev[13]) + (ev[14] + ev[15]);
    float ps = (s0 + s1) + (s2 + s3);
    ps += __shfl_xor(ps, 32);
    lsum += ps;

    u32 c0 = cvtpk_bf16(ev[0],  ev[1]),  c1 = cvtpk_bf16(ev[2],  ev[3]);
    u32 c2 = cvtpk_bf16(ev[4],  ev[5]),  c3 = cvtpk_bf16(ev[6],  ev[7]);
    u32 c4 = cvtpk_bf16(ev[8],  ev[9]),  c5 = cvtpk_bf16(ev[10], ev[11]);
    u32 c6 = cvtpk_bf16(ev[12], ev[13]), c7 = cvtpk_bf16(ev[14], ev[15]);
    plane_swap(c0, c2);
    plane_swap(c1, c3);
    plane_swap(c4, c6);
    plane_swap(c5, c7);
    union { u32 u[4]; bf16x8 v; } pb0u, pb1u;
    pb0u.u[0] = c0; pb0u.u[1] = c1; pb0u.u[2] = c2; pb0u.u[3] = c3;
    pb1u.u[0] = c4; pb1u.u[1] = c5; pb1u.u[2] = c6; pb1u.u[3] = c7;

    PRIO1;
    o0 = __builtin_amdgcn_mfma_f32_32x32x16_bf16(vf[0], pb0u.v, o0, 0, 0, 0);
    o1 = __builtin_amdgcn_mfma_f32_32x32x16_bf16(vf[2], pb0u.v, o1, 0, 0, 0);
    o2 = __builtin_amdgcn_mfma_f32_32x32x16_bf16(vf[4], pb0u.v, o2, 0, 0, 0);
    o3 = __builtin_amdgcn_mfma_f32_32x32x16_bf16(vf[6], pb0u.v, o3, 0, 0, 0);
    o0 = __builtin_amdgcn_mfma_f32_32x32x16_bf16(vf[1], pb1u.v, o0, 0, 0, 0);
    o1 = __builtin_amdgcn_mfma_f32_32x32x16_bf16(vf[3], pb1u.v, o1, 0, 0, 0);
    o2 = __builtin_amdgcn_mfma_f32_32x32x16_bf16(vf[5], pb1u.v, o2, 0, 0, 0);
    o3 = __builtin_amdgcn_mfma_f32_32x32x16_bf16(vf[7], pb1u.v, o3, 0, 0, 0);
    PRIO0;
  };

  LOADK(kA, 0);
  int t = 0;
  while (true) {
    {
      bf16x8 vf[8];
      LOADV(vf, t * 32);
      if (t + 1 < ntiles) LOADK(kB, (t + 1) * 32);
      TILE(kA, vf, t);
      if (++t >= ntiles) break;
    }
    {
      bf16x8 vf[8];
      LOADV(vf, t * 32);
      if (t + 1 < ntiles) LOADK(kA, (t + 1) * 32);
      TILE(kB, vf, t);
      if (++t >= ntiles) break;
    }
  }

  float inv = 1.0f / lsum;
  u16* orow = Out + (size_t)(q0 + q31) * (NH * HD) + h * HD;
#pragma unroll
  for (int dt = 0; dt < 4; ++dt) {
    const f32x16& oo = dt == 0 ? o0 : dt == 1 ? o1 : dt == 2 ? o2 : o3;
#pragma unroll
    for (int g = 0; g < 4; ++g) {
      ushort4 pk;
      pk.x = f2b(oo[g * 4 + 0] * inv);
      pk.y = f2b(oo[g * 4 + 1] * inv);
      pk.z = f2b(oo[g * 4 + 2] * inv);
      pk.w = f2b(oo[g * 4 + 3] * inv);
      *(ushort4*)&orow[dt * 32 + 8 * g + 4 * hi] = pk;
    }
  }
}

// ---------------- launcher ----------------
extern "C" void kernel_launch(void* const* d_in, const int* in_sizes, int n_in,
                              void* d_out, int out_size, void* d_ws, size_t ws_size,
                              hipStream_t stream) {
  const float* x  = (const float*)d_in[0];
  const float* Wq = (const float*)d_in[1];
  const float* Wk = (const float*)d_in[2];
  const float* Wv = (const float*)d_in[3];
  const float* Wo = (const float*)d_in[4];
  float* out = (float*)d_out;

  char* ws = (char*)d_ws;
  u16* xb   = (u16*)(ws);                           // [2048][4096]   16 MiB
  u16* wqkv = (u16*)(ws + (16ull << 20));           // [6144][4096]   48 MiB
  u16* wo_b = (u16*)(ws + (64ull << 20));           // [4096][4096]   32 MiB
  u16* qkvb = (u16*)(ws + (96ull << 20));           // [2048][6144]   24 MiB
  u16* qb   = (u16*)(ws + (16ull << 20));           // [32][2048][128] 16 MiB (over wqkv)
  u16* kbuf = (u16*)(ws + (32ull << 20));           // [8][2048][128]   4 MiB
  u16* vt   = (u16*)(ws + (36ull << 20));           // [8][128][2048]   4 MiB
  u16* ao   = (u16*)(ws);                           // [2048][4096]   16 MiB (over xb)

  const int smem_q = (256 + 192) * 256;  // 114688 B
  const int smem_o = (256 + 128) * 256;  //  98304 B
  hipFuncSetAttribute((const void*)&gemm8p<192, 48, 1>,
                      hipFuncAttributeMaxDynamicSharedMemorySize, smem_q);
  hipFuncSetAttribute((const void*)&gemm8p<128, 32, 0>,
                      hipFuncAttributeMaxDynamicSharedMemorySize, smem_o);

  cast_kernel<<<4096, 256, 0, stream>>>(x,  xb,   (2048 * 4096) / 4);
  cast_kernel<<<4096, 256, 0, stream>>>(Wq, wqkv, (4096 * 4096) / 4);
  cast_kernel<<<2048, 256, 0, stream>>>(Wk, wqkv + (size_t)4096 * 4096, (1024 * 4096) / 4);
  cast_kernel<<<2048, 256, 0, stream>>>(Wv, wqkv + (size_t)5120 * 4096, (1024 * 4096) / 4);
  cast_kernel<<<4096, 256, 0, stream>>>(Wo, wo_b, (4096 * 4096) / 4);

  gemm8p<192, 48, 1><<<256, 512, smem_q, stream>>>(xb, wqkv, qkvb, 2048, 6144, 4096);

  rope_qk<<<(32 * 2048 * 64) / 256, 256, 0, stream>>>(qkvb, qb,   0,    0.08838834764831845f);
  rope_qk<<<(8  * 2048 * 64) / 256, 256, 0, stream>>>(qkvb, kbuf, 4096, 1.0f);
  v_transpose<<<dim3(32, 64), dim3(32, 32), 0, stream>>>(qkvb, vt);

  attn_fwd<<<dim3(2048), 64, 0, stream>>>(qb, kbuf, vt, ao);

  gemm8p<128, 32, 0><<<256, 512, smem_o, stream>>>(ao, wo_b, out, 2048, 4096, 4096);
}